// Round 7
// baseline (215.531 us; speedup 1.0000x reference)
//
#include <hip/hip_runtime.h>
#include <math.h>

namespace {
constexpr int kH = 512;
constexpr int kN = 64;
constexpr int kL = 4096;
constexpr int kM = 2048;    // L/2
constexpr int kRec = 20;    // floats per (h,n) coefficient record
constexpr int kThreads = 256;
constexpr int kFftThreads = 512;
constexpr float kPi = 3.14159265358979323846f;
}

__device__ __forceinline__ int lpad(int i) { return i + (i >> 4); }

// ===================== Kernel 0: prep =====================
// One 64-thread block per head. Computes per-(h,n) SGPR-friendly coefficient
// records into d_ws.
// Record: [ai, ar2, {a0,a1,b0,b1} x {00,01,10,11}, pad, pad]
//   s_r(l) = sum_n (a0 + a1*s)/D        s = 4t^2, t = tan(pi*l/L)
//   s_i(l) = t * sum_n (b0 + b1*s)/D    D = m1*m2 (product form; the
//                                       polynomial-in-s form cancels at
//                                       resonances: ar^2 ~1e-7 vs ai^4 ~1e5)
//   a0 = -2*C1*(vr*ar + vi*ai)          a1 = 2*(vi*ai - vr*ar)
//   b0 = -4*vr*(ar^2-ai^2) - 8*vi*ar*ai b1 = -4*vr       [C1 = ar^2+ai^2]
__global__ __launch_bounds__(64)
void s4_prep(const float* __restrict__ A_real, const float* __restrict__ A_imag,
             const float* __restrict__ Bv, const float* __restrict__ Cv,
             const float* __restrict__ Pv, const float* __restrict__ inv_dt,
             float* __restrict__ cst)
{
    const int h = blockIdx.x;
    const int n = threadIdx.x;
    const int idx = h * kN + n;
    const float dt = expf(inv_dt[h]);
    const float ar = -expf(A_real[idx]) * dt;   // Re(A*dt) (negative)
    const float ai =  A_imag[idx] * dt;         // Im(A*dt)
    const float br = Bv[idx*2+0], bi = Bv[idx*2+1];
    const float cr = Cv[idx*2+0], ci = Cv[idx*2+1];
    const float pr = Pv[idx*2+0], pi = Pv[idx*2+1];
    const float v00r = (br*cr - bi*ci)*dt, v00i = (br*ci + bi*cr)*dt;  // B*C
    const float v01r = (br*pr + bi*pi)*dt, v01i = (bi*pr - br*pi)*dt;  // B*conj(P)
    const float v10r = (pr*cr - pi*ci)*dt, v10i = (pr*ci + pi*cr)*dt;  // P*C
    const float v11r = (pr*pr + pi*pi)*dt;                              // |P|^2 (real)
    const float ar2 = ar*ar;
    const float C1  = ar2 + ai*ai;
    const float dd  = ar2 - ai*ai;

    float* r = cst + idx * kRec;
    r[0]  = ai;  r[1] = ar2;
    r[2]  = -2.f*C1*(v00r*ar + v00i*ai);  r[3]  = 2.f*(v00i*ai - v00r*ar);
    r[4]  = -4.f*v00r*dd - 8.f*v00i*ar*ai; r[5]  = -4.f*v00r;
    r[6]  = -2.f*C1*(v01r*ar + v01i*ai);  r[7]  = 2.f*(v01i*ai - v01r*ar);
    r[8]  = -4.f*v01r*dd - 8.f*v01i*ar*ai; r[9]  = -4.f*v01r;
    r[10] = -2.f*C1*(v10r*ar + v10i*ai);  r[11] = 2.f*(v10i*ai - v10r*ar);
    r[12] = -4.f*v10r*dd - 8.f*v10i*ar*ai; r[13] = -4.f*v10r;
    r[14] = -2.f*C1*(v11r*ar);            r[15] = -2.f*v11r*ar;
    r[16] = -4.f*v11r*dd;                 r[17] = -4.f*v11r;
    r[18] = 0.f; r[19] = 0.f;
}

// ===================== Kernel 1: spectrum =====================
// grid = 512 heads x 4 quarters, 256 threads, 2 bins/thread (R4 structure:
// best measured TLP). Per-n constants via wave-uniform s_load; full unroll
// lets the compiler hoist s_loads several records ahead.
// Basis-separated accumulation: per (n,bin) only {6 invD ops + 16 fma},
// all 16 fmas share the single invD multiplicand; s,t applied in the tail.
__global__ __launch_bounds__(kThreads, 8)
void s4_spectrum(const float* __restrict__ cst, float2* __restrict__ Xg)
{
    const int h   = blockIdx.x >> 2;
    const int q   = blockIdx.x & 3;
    const int tid = threadIdx.x;
    const int la  = q * 512 + tid;    // bins la and la+256

    float tv[2], t2v[2], sv[2];
    #pragma unroll
    for (int b = 0; b < 2; ++b) {
        const int l = la + 256 * b;
        float sn, cn;
        sincosf((float)l * (kPi / (float)kL), &sn, &cn);
        tv[b]  = sn / cn;            // tan(pi*l/L), finite for l <= 2047
        t2v[b] = 2.f * tv[b];
        sv[b]  = t2v[b] * t2v[b];    // s = 4t^2
    }

    // [bin][product {00,01,10,11}]
    float A0[2][4] = {{0,0,0,0},{0,0,0,0}};
    float A1[2][4] = {{0,0,0,0},{0,0,0,0}};
    float B0[2][4] = {{0,0,0,0},{0,0,0,0}};
    float B1[2][4] = {{0,0,0,0},{0,0,0,0}};

    const float* rec = cst + (size_t)h * kN * kRec;
    #pragma unroll
    for (int n = 0; n < kN; ++n) {
        const float* r = rec + n * kRec;   // wave-uniform -> s_load
        const float ai = r[0], ar2 = r[1];
        #pragma unroll
        for (int b = 0; b < 2; ++b) {
            const float w1 = t2v[b] - ai, w2 = t2v[b] + ai;
            const float m1 = fmaf(w1, w1, ar2), m2 = fmaf(w2, w2, ar2);
            const float invD = __builtin_amdgcn_rcpf(m1 * m2);
            #pragma unroll
            for (int p = 0; p < 4; ++p) {
                A0[b][p] = fmaf(r[2 + 4*p], invD, A0[b][p]);
                A1[b][p] = fmaf(r[3 + 4*p], invD, A1[b][p]);
                B0[b][p] = fmaf(r[4 + 4*p], invD, B0[b][p]);
                B1[b][p] = fmaf(r[5 + 4*p], invD, B1[b][p]);
            }
        }
    }

    #pragma unroll
    for (int b = 0; b < 2; ++b) {
        const int l = la + 256 * b;
        const float t = tv[b], s = sv[b];
        const float s00r = fmaf(s, A1[b][0], A0[b][0]);
        const float s00i = t * fmaf(s, B1[b][0], B0[b][0]);
        const float s01r = fmaf(s, A1[b][1], A0[b][1]);
        const float s01i = t * fmaf(s, B1[b][1], B0[b][1]);
        const float s10r = fmaf(s, A1[b][2], A0[b][2]);
        const float s10i = t * fmaf(s, B1[b][2], B0[b][2]);
        const float s11r = fmaf(s, A1[b][3], A0[b][3]);
        const float s11i = t * fmaf(s, B1[b][3], B0[b][3]);
        const float nr = s01r*s10r - s01i*s10i;
        const float ni = s01r*s10i + s01i*s10r;
        const float dr = 1.f + s11r, di = s11i;
        const float qd = __builtin_amdgcn_rcpf(fmaf(dr, dr, di*di));
        const float wr = (nr*dr + ni*di) * qd;
        const float wi = (ni*dr - nr*di) * qd;
        const float gr = s00r - wr, gi = s00i - wi;
        // k_f = g * (1 + i*t)
        Xg[h*kM + l] = make_float2(fmaf(-gi, t, gr), fmaf(gr, t, gi));
    }
}

// ===================== Kernel 2: irfft =====================
// One 512-thread block per head. Packed-real 2048-pt inverse complex DFT in
// LDS with index padding i+(i>>4) to break power-of-2 bank aliasing.
// Nyquist bin computed in-kernel: k_f[2048] = sum_n Re(B*C)*dt (real).
__global__ __launch_bounds__(kFftThreads)
void s4_ifft(const float* __restrict__ Bv,
             const float* __restrict__ Cv,
             const float* __restrict__ inv_dt,
             float* __restrict__ out)
{
    __shared__ float2 W2[kM + kM / 16];
    __shared__ float2 TW[kM / 2 + kM / 32];
    __shared__ float  XnyqR;

    const int h   = blockIdx.x;
    const int tid = threadIdx.x;
    const float2* Xg = (const float2*)(out + (size_t)h * kL);

    if (tid < kN) {   // wave 0: Nyquist bin
        const int idx = h * kN + tid;
        const float dt = expf(inv_dt[h]);
        const float br = Bv[idx*2+0], bi = Bv[idx*2+1];
        const float cr = Cv[idx*2+0], ci = Cv[idx*2+1];
        float vr = (br*cr - bi*ci) * dt;
        #pragma unroll
        for (int off = 32; off > 0; off >>= 1) vr += __shfl_down(vr, off, 64);
        if (tid == 0) XnyqR = vr;
    }
    for (int j = tid; j < kM / 2; j += kFftThreads) {
        float s, c;
        sincosf((2.0f * kPi / (float)kM) * (float)j, &s, &c);
        TW[lpad(j)] = make_float2(c, s);       // e^{+2pi i j / 2048}
    }
    __syncthreads();

    // build Z (bit-reversed) from global X:
    // E = (X[k]+conj(X[M-k]))/2 ; O = e^{+2pi i k/L}*(X[k]-conj(X[M-k]))/2
    // Z[k] = (Er-Oi, Ei+Or); Z[M-k] = (Er+Oi, Or-Ei)
    for (int k = tid; k <= kM / 2; k += kFftThreads) {
        const float2 Xa = Xg[k];
        const float2 Xb = (k == 0) ? make_float2(XnyqR, 0.0f) : Xg[kM - k];
        const float Er = 0.5f * (Xa.x + Xb.x);
        const float Ei = 0.5f * (Xa.y - Xb.y);
        const float Dr = 0.5f * (Xa.x - Xb.x);
        const float Di = 0.5f * (Xa.y + Xb.y);
        float s, c;
        sincosf((2.0f * kPi / (float)kL) * (float)k, &s, &c);
        const float Or = c * Dr - s * Di;
        const float Oi = c * Di + s * Dr;
        const int rk = (int)(__brev((unsigned)k) >> 21);          // 11-bit reversal
        W2[lpad(rk)] = make_float2(Er - Oi, Ei + Or);
        if (k != 0 && k != kM / 2) {
            const int rmk = (int)(__brev((unsigned)(kM - k)) >> 21);
            W2[lpad(rmk)] = make_float2(Er + Oi, Or - Ei);
        }
    }
    __syncthreads();

    for (int hs = 1; hs < kM; hs <<= 1) {
        const int tw_stride = (kM / 2) / hs;
        for (int j = tid; j < kM / 2; j += kFftThreads) {
            const int pos = j & (hs - 1);
            const int grp = j / hs;
            const int i0  = grp * 2 * hs + pos;
            const int i1  = i0 + hs;
            const float2 tw = TW[lpad(pos * tw_stride)];
            const float2 a = W2[lpad(i0)];
            const float2 b = W2[lpad(i1)];
            const float tr = tw.x * b.x - tw.y * b.y;
            const float ti = tw.x * b.y + tw.y * b.x;
            W2[lpad(i0)] = make_float2(a.x + tr, a.y + ti);
            W2[lpad(i1)] = make_float2(a.x - tr, a.y - ti);
        }
        __syncthreads();
    }

    const float invM = 1.0f / (float)kM;
    float2* out2 = (float2*)(out + (size_t)h * kL);
    for (int n = tid; n < kM; n += kFftThreads) {
        const float2 zn = W2[lpad(n)];
        out2[n] = make_float2(zn.x * invM, zn.y * invM);
    }
}

extern "C" void kernel_launch(void* const* d_in, const int* in_sizes, int n_in,
                              void* d_out, int out_size, void* d_ws, size_t ws_size,
                              hipStream_t stream) {
    const float* A_real = (const float*)d_in[0];
    const float* A_imag = (const float*)d_in[1];
    const float* B      = (const float*)d_in[2];
    const float* C      = (const float*)d_in[3];
    const float* P      = (const float*)d_in[4];
    const float* inv_dt = (const float*)d_in[5];
    float* out = (float*)d_out;

    float* cst = (float*)d_ws;                        // 512*64*20 floats = 2.62 MB

    s4_prep<<<dim3(kH), dim3(64), 0, stream>>>(A_real, A_imag, B, C, P, inv_dt,
                                               cst);
    s4_spectrum<<<dim3(kH * 4), dim3(kThreads), 0, stream>>>(cst, (float2*)out);
    s4_ifft<<<dim3(kH), dim3(kFftThreads), 0, stream>>>(B, C, inv_dt, out);
}

// Round 8
// 125.286 us; speedup vs baseline: 1.7203x; 1.7203x over previous
//
#include <hip/hip_runtime.h>
#include <math.h>

namespace {
constexpr int kH = 512;
constexpr int kN = 64;
constexpr int kL = 4096;
constexpr int kM = 2048;    // L/2
constexpr int kRec = 20;    // floats per (h,n) coefficient record
constexpr int kThreads = 256;
constexpr int kFftThreads = 512;
constexpr float kPi = 3.14159265358979323846f;
}

__device__ __forceinline__ int lpad(int i) { return i + (i >> 4); }

// ===================== Kernel 0: prep =====================
// One 64-thread block per head. Computes per-(h,n) SGPR-friendly coefficient
// records into d_ws.
// Record: [ai, ar2, {a0,a1,b0,b1} x {00,01,10,11}, pad, pad]
//   s_r(l) = sum_n (a0 + a1*s)/D        s = 4t^2, t = tan(pi*l/L)
//   s_i(l) = t * sum_n (b0 + b1*s)/D    D = m1*m2 (product form; the
//                                       polynomial-in-s form cancels at
//                                       resonances: ar^2 ~1e-7 vs ai^4 ~1e5)
//   a0 = -2*C1*(vr*ar + vi*ai)          a1 = 2*(vi*ai - vr*ar)
//   b0 = -4*vr*(ar^2-ai^2) - 8*vi*ar*ai b1 = -4*vr       [C1 = ar^2+ai^2]
__global__ __launch_bounds__(64)
void s4_prep(const float* __restrict__ A_real, const float* __restrict__ A_imag,
             const float* __restrict__ Bv, const float* __restrict__ Cv,
             const float* __restrict__ Pv, const float* __restrict__ inv_dt,
             float* __restrict__ cst)
{
    const int h = blockIdx.x;
    const int n = threadIdx.x;
    const int idx = h * kN + n;
    const float dt = expf(inv_dt[h]);
    const float ar = -expf(A_real[idx]) * dt;   // Re(A*dt) (negative)
    const float ai =  A_imag[idx] * dt;         // Im(A*dt)
    const float br = Bv[idx*2+0], bi = Bv[idx*2+1];
    const float cr = Cv[idx*2+0], ci = Cv[idx*2+1];
    const float pr = Pv[idx*2+0], pi = Pv[idx*2+1];
    const float v00r = (br*cr - bi*ci)*dt, v00i = (br*ci + bi*cr)*dt;  // B*C
    const float v01r = (br*pr + bi*pi)*dt, v01i = (bi*pr - br*pi)*dt;  // B*conj(P)
    const float v10r = (pr*cr - pi*ci)*dt, v10i = (pr*ci + pi*cr)*dt;  // P*C
    const float v11r = (pr*pr + pi*pi)*dt;                              // |P|^2 (real)
    const float ar2 = ar*ar;
    const float C1  = ar2 + ai*ai;
    const float dd  = ar2 - ai*ai;

    float* r = cst + idx * kRec;
    r[0]  = ai;  r[1] = ar2;
    r[2]  = -2.f*C1*(v00r*ar + v00i*ai);  r[3]  = 2.f*(v00i*ai - v00r*ar);
    r[4]  = -4.f*v00r*dd - 8.f*v00i*ar*ai; r[5]  = -4.f*v00r;
    r[6]  = -2.f*C1*(v01r*ar + v01i*ai);  r[7]  = 2.f*(v01i*ai - v01r*ar);
    r[8]  = -4.f*v01r*dd - 8.f*v01i*ar*ai; r[9]  = -4.f*v01r;
    r[10] = -2.f*C1*(v10r*ar + v10i*ai);  r[11] = 2.f*(v10i*ai - v10r*ar);
    r[12] = -4.f*v10r*dd - 8.f*v10i*ar*ai; r[13] = -4.f*v10r;
    r[14] = -2.f*C1*(v11r*ar);            r[15] = -2.f*v11r*ar;
    r[16] = -4.f*v11r*dd;                 r[17] = -4.f*v11r;
    r[18] = 0.f; r[19] = 0.f;
}

// ===================== Kernel 1: spectrum =====================
// grid = 512 heads x 4 quarters (R4's winning TLP), 256 threads,
// 2 bins/thread. Per-n constants via wave-uniform s_load. The n-loop is
// blocked by 4 with the records copied to locals FIRST, so 4 records'
// s_loads are in flight simultaneously (R4's unroll-2 had only 2).
// NO min-waves launch bound: R7 proved pinning it to 8 forces VGPR=32 and
// catastrophic scratch spills (WRITE_SIZE 8->50 MB).
__global__ __launch_bounds__(kThreads)
void s4_spectrum(const float* __restrict__ cst, float2* __restrict__ Xg)
{
    const int h   = blockIdx.x >> 2;
    const int q   = blockIdx.x & 3;
    const int tid = threadIdx.x;
    const int la  = q * 512 + tid;    // bins la and la+256

    float tv[2], t2v[2], sv[2];
    #pragma unroll
    for (int b = 0; b < 2; ++b) {
        const int l = la + 256 * b;
        float sn, cn;
        sincosf((float)l * (kPi / (float)kL), &sn, &cn);
        tv[b]  = sn / cn;            // tan(pi*l/L), finite for l <= 2047
        t2v[b] = 2.f * tv[b];
        sv[b]  = t2v[b] * t2v[b];    // s = 4t^2
    }

    // [bin][product {00,01,10,11}] basis-separated partial sums
    float A0[2][4] = {{0,0,0,0},{0,0,0,0}};
    float A1[2][4] = {{0,0,0,0},{0,0,0,0}};
    float B0[2][4] = {{0,0,0,0},{0,0,0,0}};
    float B1[2][4] = {{0,0,0,0},{0,0,0,0}};

    const float* rec = cst + (size_t)h * kN * kRec;
    #pragma unroll 1
    for (int n0 = 0; n0 < kN; n0 += 4) {
        // stage 4 records into (scalar) locals -- 4 s_load groups in flight
        float rr[4][18];
        #pragma unroll
        for (int j = 0; j < 4; ++j) {
            const float* r = rec + (n0 + j) * kRec;
            #pragma unroll
            for (int k = 0; k < 18; ++k) rr[j][k] = r[k];
        }
        #pragma unroll
        for (int j = 0; j < 4; ++j) {
            const float ai = rr[j][0], ar2 = rr[j][1];
            #pragma unroll
            for (int b = 0; b < 2; ++b) {
                const float w1 = t2v[b] - ai, w2 = t2v[b] + ai;
                const float m1 = fmaf(w1, w1, ar2), m2 = fmaf(w2, w2, ar2);
                const float invD = __builtin_amdgcn_rcpf(m1 * m2);
                #pragma unroll
                for (int p = 0; p < 4; ++p) {
                    A0[b][p] = fmaf(rr[j][2 + 4*p], invD, A0[b][p]);
                    A1[b][p] = fmaf(rr[j][3 + 4*p], invD, A1[b][p]);
                    B0[b][p] = fmaf(rr[j][4 + 4*p], invD, B0[b][p]);
                    B1[b][p] = fmaf(rr[j][5 + 4*p], invD, B1[b][p]);
                }
            }
        }
    }

    #pragma unroll
    for (int b = 0; b < 2; ++b) {
        const int l = la + 256 * b;
        const float t = tv[b], s = sv[b];
        const float s00r = fmaf(s, A1[b][0], A0[b][0]);
        const float s00i = t * fmaf(s, B1[b][0], B0[b][0]);
        const float s01r = fmaf(s, A1[b][1], A0[b][1]);
        const float s01i = t * fmaf(s, B1[b][1], B0[b][1]);
        const float s10r = fmaf(s, A1[b][2], A0[b][2]);
        const float s10i = t * fmaf(s, B1[b][2], B0[b][2]);
        const float s11r = fmaf(s, A1[b][3], A0[b][3]);
        const float s11i = t * fmaf(s, B1[b][3], B0[b][3]);
        const float nr = s01r*s10r - s01i*s10i;
        const float ni = s01r*s10i + s01i*s10r;
        const float dr = 1.f + s11r, di = s11i;
        const float qd = __builtin_amdgcn_rcpf(fmaf(dr, dr, di*di));
        const float wr = (nr*dr + ni*di) * qd;
        const float wi = (ni*dr - nr*di) * qd;
        const float gr = s00r - wr, gi = s00i - wi;
        // k_f = g * (1 + i*t)
        Xg[h*kM + l] = make_float2(fmaf(-gi, t, gr), fmaf(gr, t, gi));
    }
}

// ===================== Kernel 2: irfft =====================
// One 512-thread block per head. Packed-real 2048-pt inverse complex DFT in
// LDS with index padding i+(i>>4) to break power-of-2 bank aliasing.
// Nyquist bin computed in-kernel: k_f[2048] = sum_n Re(B*C)*dt (real).
__global__ __launch_bounds__(kFftThreads)
void s4_ifft(const float* __restrict__ Bv,
             const float* __restrict__ Cv,
             const float* __restrict__ inv_dt,
             float* __restrict__ out)
{
    __shared__ float2 W2[kM + kM / 16];
    __shared__ float2 TW[kM / 2 + kM / 32];
    __shared__ float  XnyqR;

    const int h   = blockIdx.x;
    const int tid = threadIdx.x;
    const float2* Xg = (const float2*)(out + (size_t)h * kL);

    if (tid < kN) {   // wave 0: Nyquist bin
        const int idx = h * kN + tid;
        const float dt = expf(inv_dt[h]);
        const float br = Bv[idx*2+0], bi = Bv[idx*2+1];
        const float cr = Cv[idx*2+0], ci = Cv[idx*2+1];
        float vr = (br*cr - bi*ci) * dt;
        #pragma unroll
        for (int off = 32; off > 0; off >>= 1) vr += __shfl_down(vr, off, 64);
        if (tid == 0) XnyqR = vr;
    }
    for (int j = tid; j < kM / 2; j += kFftThreads) {
        float s, c;
        sincosf((2.0f * kPi / (float)kM) * (float)j, &s, &c);
        TW[lpad(j)] = make_float2(c, s);       // e^{+2pi i j / 2048}
    }
    __syncthreads();

    // build Z (bit-reversed) from global X:
    // E = (X[k]+conj(X[M-k]))/2 ; O = e^{+2pi i k/L}*(X[k]-conj(X[M-k]))/2
    // Z[k] = (Er-Oi, Ei+Or); Z[M-k] = (Er+Oi, Or-Ei)
    for (int k = tid; k <= kM / 2; k += kFftThreads) {
        const float2 Xa = Xg[k];
        const float2 Xb = (k == 0) ? make_float2(XnyqR, 0.0f) : Xg[kM - k];
        const float Er = 0.5f * (Xa.x + Xb.x);
        const float Ei = 0.5f * (Xa.y - Xb.y);
        const float Dr = 0.5f * (Xa.x - Xb.x);
        const float Di = 0.5f * (Xa.y + Xb.y);
        float s, c;
        sincosf((2.0f * kPi / (float)kL) * (float)k, &s, &c);
        const float Or = c * Dr - s * Di;
        const float Oi = c * Di + s * Dr;
        const int rk = (int)(__brev((unsigned)k) >> 21);          // 11-bit reversal
        W2[lpad(rk)] = make_float2(Er - Oi, Ei + Or);
        if (k != 0 && k != kM / 2) {
            const int rmk = (int)(__brev((unsigned)(kM - k)) >> 21);
            W2[lpad(rmk)] = make_float2(Er + Oi, Or - Ei);
        }
    }
    __syncthreads();

    for (int hs = 1; hs < kM; hs <<= 1) {
        const int tw_stride = (kM / 2) / hs;
        for (int j = tid; j < kM / 2; j += kFftThreads) {
            const int pos = j & (hs - 1);
            const int grp = j / hs;
            const int i0  = grp * 2 * hs + pos;
            const int i1  = i0 + hs;
            const float2 tw = TW[lpad(pos * tw_stride)];
            const float2 a = W2[lpad(i0)];
            const float2 b = W2[lpad(i1)];
            const float tr = tw.x * b.x - tw.y * b.y;
            const float ti = tw.x * b.y + tw.y * b.x;
            W2[lpad(i0)] = make_float2(a.x + tr, a.y + ti);
            W2[lpad(i1)] = make_float2(a.x - tr, a.y - ti);
        }
        __syncthreads();
    }

    const float invM = 1.0f / (float)kM;
    float2* out2 = (float2*)(out + (size_t)h * kL);
    for (int n = tid; n < kM; n += kFftThreads) {
        const float2 zn = W2[lpad(n)];
        out2[n] = make_float2(zn.x * invM, zn.y * invM);
    }
}

extern "C" void kernel_launch(void* const* d_in, const int* in_sizes, int n_in,
                              void* d_out, int out_size, void* d_ws, size_t ws_size,
                              hipStream_t stream) {
    const float* A_real = (const float*)d_in[0];
    const float* A_imag = (const float*)d_in[1];
    const float* B      = (const float*)d_in[2];
    const float* C      = (const float*)d_in[3];
    const float* P      = (const float*)d_in[4];
    const float* inv_dt = (const float*)d_in[5];
    float* out = (float*)d_out;

    float* cst = (float*)d_ws;                        // 512*64*20 floats = 2.62 MB

    s4_prep<<<dim3(kH), dim3(64), 0, stream>>>(A_real, A_imag, B, C, P, inv_dt,
                                               cst);
    s4_spectrum<<<dim3(kH * 4), dim3(kThreads), 0, stream>>>(cst, (float2*)out);
    s4_ifft<<<dim3(kH), dim3(kFftThreads), 0, stream>>>(B, C, inv_dt, out);
}

// Round 9
// 113.433 us; speedup vs baseline: 1.9001x; 1.1045x over previous
//
#include <hip/hip_runtime.h>
#include <math.h>

namespace {
constexpr int kH = 512;
constexpr int kN = 64;
constexpr int kL = 4096;
constexpr int kM = 2048;      // L/2
constexpr int kPairRec = 40;  // floats per n-PAIR record (160 B, dwordx16-friendly)
constexpr int kThreads = 256;
constexpr int kFftThreads = 512;
constexpr float kPi = 3.14159265358979323846f;
}

typedef float v2f __attribute__((ext_vector_type(2)));

__device__ __forceinline__ int lpad(int i) { return i + (i >> 4); }
__device__ __forceinline__ v2f fma2(v2f a, v2f b, v2f c) {
    return __builtin_elementwise_fma(a, b, c);
}

// ===================== Kernel 0: prep =====================
// One 64-thread block per head. Pair-interleaved coefficient records:
// record for n-pair j=(n>>1) holds, at float offsets:
//   [0..1]  ai(2j), ai(2j+1)      [2..3] ar2(2j), ar2(2j+1)
//   [4+2k .. 5+2k] coeff k for (2j, 2j+1),  k = 4p + {a0,a1,b0,b1}
// so every coefficient PAIR is a 64-bit-aligned consecutive scalar pair ->
// legal SGPR-pair operand of v_pk_fma_f32 (pair across n, zero broadcast).
//   s_r(l) = sum_n (a0 + a1*s)/D        s = 4t^2, t = tan(pi*l/L)
//   s_i(l) = t * sum_n (b0 + b1*s)/D    D = m1*m2, m = ar^2 + (2t -+ ai)^2
//   (D kept in PRODUCT form: the polynomial-in-s expansion cancels
//    catastrophically at resonances: ar^2 ~2.5e-7 while ai^4 ~1.5e5)
//   a0 = -2*C1*(vr*ar + vi*ai)          a1 = 2*(vi*ai - vr*ar)
//   b0 = -4*vr*(ar^2-ai^2) - 8*vi*ar*ai b1 = -4*vr       [C1 = ar^2+ai^2]
__global__ __launch_bounds__(64)
void s4_prep(const float* __restrict__ A_real, const float* __restrict__ A_imag,
             const float* __restrict__ Bv, const float* __restrict__ Cv,
             const float* __restrict__ Pv, const float* __restrict__ inv_dt,
             float* __restrict__ cst)
{
    const int h = blockIdx.x;
    const int n = threadIdx.x;
    const int idx = h * kN + n;
    const float dt = expf(inv_dt[h]);
    const float ar = -expf(A_real[idx]) * dt;   // Re(A*dt) (negative)
    const float ai =  A_imag[idx] * dt;         // Im(A*dt)
    const float br = Bv[idx*2+0], bi = Bv[idx*2+1];
    const float cr = Cv[idx*2+0], ci = Cv[idx*2+1];
    const float pr = Pv[idx*2+0], pi = Pv[idx*2+1];
    const float v00r = (br*cr - bi*ci)*dt, v00i = (br*ci + bi*cr)*dt;  // B*C
    const float v01r = (br*pr + bi*pi)*dt, v01i = (bi*pr - br*pi)*dt;  // B*conj(P)
    const float v10r = (pr*cr - pi*ci)*dt, v10i = (pr*ci + pi*cr)*dt;  // P*C
    const float v11r = (pr*pr + pi*pi)*dt;                              // |P|^2 (real)
    const float ar2 = ar*ar;
    const float C1  = ar2 + ai*ai;
    const float dd  = ar2 - ai*ai;

    float co[16];
    co[0]  = -2.f*C1*(v00r*ar + v00i*ai);   co[1]  = 2.f*(v00i*ai - v00r*ar);
    co[2]  = -4.f*v00r*dd - 8.f*v00i*ar*ai; co[3]  = -4.f*v00r;
    co[4]  = -2.f*C1*(v01r*ar + v01i*ai);   co[5]  = 2.f*(v01i*ai - v01r*ar);
    co[6]  = -4.f*v01r*dd - 8.f*v01i*ar*ai; co[7]  = -4.f*v01r;
    co[8]  = -2.f*C1*(v10r*ar + v10i*ai);   co[9]  = 2.f*(v10i*ai - v10r*ar);
    co[10] = -4.f*v10r*dd - 8.f*v10i*ar*ai; co[11] = -4.f*v10r;
    co[12] = -2.f*C1*(v11r*ar);             co[13] = -2.f*v11r*ar;
    co[14] = -4.f*v11r*dd;                  co[15] = -4.f*v11r;

    float* base = cst + ((size_t)h * (kN/2) + (n >> 1)) * kPairRec + (n & 1);
    base[0] = ai;
    base[2] = ar2;
    #pragma unroll
    for (int k = 0; k < 16; ++k) base[4 + 2*k] = co[k];
    // floats 36..39 unused padding
}

// ===================== Kernel 1: spectrum =====================
// grid = 512 heads x 4 quarters, 256 threads, 2 bins/thread (R4/R8 winning
// TLP). All arithmetic packed across adjacent n (v_pk_*_f32): coefficient
// pairs arrive as SGPR pairs via wave-uniform s_load; accumulators are v2f
// even/odd-n partial sums, horizontally reduced in the tail.
// NO min-waves launch bound (R7: pinning caused scratch-spill disaster).
__global__ __launch_bounds__(kThreads)
void s4_spectrum(const float* __restrict__ cst, float2* __restrict__ Xg)
{
    const int h   = blockIdx.x >> 2;
    const int q   = blockIdx.x & 3;
    const int tid = threadIdx.x;
    const int la  = q * 512 + tid;    // bins la and la+256

    float tv[2], sv[2];
    v2f t2p[2];
    #pragma unroll
    for (int b = 0; b < 2; ++b) {
        const int l = la + 256 * b;
        float sn, cn;
        sincosf((float)l * (kPi / (float)kL), &sn, &cn);
        tv[b] = sn / cn;                     // tan(pi*l/L), finite for l<=2047
        const float t2 = 2.f * tv[b];
        sv[b] = t2 * t2;                     // s = 4t^2
        t2p[b] = (v2f){t2, t2};
    }

    // [bin][product {00,01,10,11}] packed even/odd-n partial sums
    v2f A0[2][4], A1[2][4], B0[2][4], B1[2][4];
    #pragma unroll
    for (int b = 0; b < 2; ++b)
        #pragma unroll
        for (int p = 0; p < 4; ++p) {
            A0[b][p] = (v2f){0.f, 0.f}; A1[b][p] = (v2f){0.f, 0.f};
            B0[b][p] = (v2f){0.f, 0.f}; B1[b][p] = (v2f){0.f, 0.f};
        }

    const v2f* rec = (const v2f*)(cst + (size_t)h * (kN/2) * kPairRec);
    #pragma unroll 2
    for (int j = 0; j < kN/2; ++j) {
        const v2f* r = rec + j * (kPairRec/2);   // wave-uniform -> s_load
        const v2f aip  = r[0];
        const v2f ar2p = r[1];
        #pragma unroll
        for (int b = 0; b < 2; ++b) {
            const v2f w1 = t2p[b] - aip;
            const v2f w2 = t2p[b] + aip;
            const v2f m1 = fma2(w1, w1, ar2p);
            const v2f m2 = fma2(w2, w2, ar2p);
            const v2f D  = m1 * m2;
            v2f qv;
            qv.x = __builtin_amdgcn_rcpf(D.x);
            qv.y = __builtin_amdgcn_rcpf(D.y);
            #pragma unroll
            for (int p = 0; p < 4; ++p) {
                A0[b][p] = fma2(r[2 + 4*p + 0], qv, A0[b][p]);
                A1[b][p] = fma2(r[2 + 4*p + 1], qv, A1[b][p]);
                B0[b][p] = fma2(r[2 + 4*p + 2], qv, B0[b][p]);
                B1[b][p] = fma2(r[2 + 4*p + 3], qv, B1[b][p]);
            }
        }
    }

    #pragma unroll
    for (int b = 0; b < 2; ++b) {
        const int l = la + 256 * b;
        const float t = tv[b];
        const v2f sp = (v2f){sv[b], sv[b]};
        const v2f r00 = fma2(sp, A1[b][0], A0[b][0]);
        const v2f i00 = fma2(sp, B1[b][0], B0[b][0]);
        const v2f r01 = fma2(sp, A1[b][1], A0[b][1]);
        const v2f i01 = fma2(sp, B1[b][1], B0[b][1]);
        const v2f r10 = fma2(sp, A1[b][2], A0[b][2]);
        const v2f i10 = fma2(sp, B1[b][2], B0[b][2]);
        const v2f r11 = fma2(sp, A1[b][3], A0[b][3]);
        const v2f i11 = fma2(sp, B1[b][3], B0[b][3]);
        const float s00r = r00.x + r00.y, s00i = t * (i00.x + i00.y);
        const float s01r = r01.x + r01.y, s01i = t * (i01.x + i01.y);
        const float s10r = r10.x + r10.y, s10i = t * (i10.x + i10.y);
        const float s11r = r11.x + r11.y, s11i = t * (i11.x + i11.y);
        const float nr = s01r*s10r - s01i*s10i;
        const float ni = s01r*s10i + s01i*s10r;
        const float dr = 1.f + s11r, di = s11i;
        const float qd = __builtin_amdgcn_rcpf(fmaf(dr, dr, di*di));
        const float wr = (nr*dr + ni*di) * qd;
        const float wi = (ni*dr - nr*di) * qd;
        const float gr = s00r - wr, gi = s00i - wi;
        // k_f = g * (1 + i*t)
        Xg[h*kM + l] = make_float2(fmaf(-gi, t, gr), fmaf(gr, t, gi));
    }
}

// ===================== Kernel 2: irfft =====================
// One 512-thread block per head. Packed-real 2048-pt inverse complex DFT in
// LDS with index padding i+(i>>4) to break power-of-2 bank aliasing.
// Nyquist bin computed in-kernel: k_f[2048] = sum_n Re(B*C)*dt (real).
__global__ __launch_bounds__(kFftThreads)
void s4_ifft(const float* __restrict__ Bv,
             const float* __restrict__ Cv,
             const float* __restrict__ inv_dt,
             float* __restrict__ out)
{
    __shared__ float2 W2[kM + kM / 16];
    __shared__ float2 TW[kM / 2 + kM / 32];
    __shared__ float  XnyqR;

    const int h   = blockIdx.x;
    const int tid = threadIdx.x;
    const float2* Xg = (const float2*)(out + (size_t)h * kL);

    if (tid < kN) {   // wave 0: Nyquist bin
        const int idx = h * kN + tid;
        const float dt = expf(inv_dt[h]);
        const float br = Bv[idx*2+0], bi = Bv[idx*2+1];
        const float cr = Cv[idx*2+0], ci = Cv[idx*2+1];
        float vr = (br*cr - bi*ci) * dt;
        #pragma unroll
        for (int off = 32; off > 0; off >>= 1) vr += __shfl_down(vr, off, 64);
        if (tid == 0) XnyqR = vr;
    }
    for (int j = tid; j < kM / 2; j += kFftThreads) {
        float s, c;
        sincosf((2.0f * kPi / (float)kM) * (float)j, &s, &c);
        TW[lpad(j)] = make_float2(c, s);       // e^{+2pi i j / 2048}
    }
    __syncthreads();

    // build Z (bit-reversed) from global X:
    // E = (X[k]+conj(X[M-k]))/2 ; O = e^{+2pi i k/L}*(X[k]-conj(X[M-k]))/2
    // Z[k] = (Er-Oi, Ei+Or); Z[M-k] = (Er+Oi, Or-Ei)
    for (int k = tid; k <= kM / 2; k += kFftThreads) {
        const float2 Xa = Xg[k];
        const float2 Xb = (k == 0) ? make_float2(XnyqR, 0.0f) : Xg[kM - k];
        const float Er = 0.5f * (Xa.x + Xb.x);
        const float Ei = 0.5f * (Xa.y - Xb.y);
        const float Dr = 0.5f * (Xa.x - Xb.x);
        const float Di = 0.5f * (Xa.y + Xb.y);
        float s, c;
        sincosf((2.0f * kPi / (float)kL) * (float)k, &s, &c);
        const float Or = c * Dr - s * Di;
        const float Oi = c * Di + s * Dr;
        const int rk = (int)(__brev((unsigned)k) >> 21);          // 11-bit reversal
        W2[lpad(rk)] = make_float2(Er - Oi, Ei + Or);
        if (k != 0 && k != kM / 2) {
            const int rmk = (int)(__brev((unsigned)(kM - k)) >> 21);
            W2[lpad(rmk)] = make_float2(Er + Oi, Or - Ei);
        }
    }
    __syncthreads();

    for (int hs = 1; hs < kM; hs <<= 1) {
        const int tw_stride = (kM / 2) / hs;
        for (int j = tid; j < kM / 2; j += kFftThreads) {
            const int pos = j & (hs - 1);
            const int grp = j / hs;
            const int i0  = grp * 2 * hs + pos;
            const int i1  = i0 + hs;
            const float2 tw = TW[lpad(pos * tw_stride)];
            const float2 a = W2[lpad(i0)];
            const float2 b = W2[lpad(i1)];
            const float tr = tw.x * b.x - tw.y * b.y;
            const float ti = tw.x * b.y + tw.y * b.x;
            W2[lpad(i0)] = make_float2(a.x + tr, a.y + ti);
            W2[lpad(i1)] = make_float2(a.x - tr, a.y - ti);
        }
        __syncthreads();
    }

    const float invM = 1.0f / (float)kM;
    float2* out2 = (float2*)(out + (size_t)h * kL);
    for (int n = tid; n < kM; n += kFftThreads) {
        const float2 zn = W2[lpad(n)];
        out2[n] = make_float2(zn.x * invM, zn.y * invM);
    }
}

extern "C" void kernel_launch(void* const* d_in, const int* in_sizes, int n_in,
                              void* d_out, int out_size, void* d_ws, size_t ws_size,
                              hipStream_t stream) {
    const float* A_real = (const float*)d_in[0];
    const float* A_imag = (const float*)d_in[1];
    const float* B      = (const float*)d_in[2];
    const float* C      = (const float*)d_in[3];
    const float* P      = (const float*)d_in[4];
    const float* inv_dt = (const float*)d_in[5];
    float* out = (float*)d_out;

    float* cst = (float*)d_ws;     // 512*32*40 floats = 2.62 MB

    s4_prep<<<dim3(kH), dim3(64), 0, stream>>>(A_real, A_imag, B, C, P, inv_dt,
                                               cst);
    s4_spectrum<<<dim3(kH * 4), dim3(kThreads), 0, stream>>>(cst, (float2*)out);
    s4_ifft<<<dim3(kH), dim3(kFftThreads), 0, stream>>>(B, C, inv_dt, out);
}